// Round 4
// baseline (122.353 us; speedup 1.0000x reference)
//
#include <hip/hip_runtime.h>
#include <hip/hip_bf16.h>

// NT-Xent (SimCLR) fused loss, MI355X gfx950. Round 12: no vmem in barriers.
// r11 post-mortem: fast exp recovered the r9 regression (dur 83.7us, simclr
// ~38us) but busy-pipe accounting leaves ~30us of stall. Theory: every
// per-tile __syncthreads (s_waitcnt vmcnt(0)) drains the column-sum
// atomicAdds issued right before it -- device-scope atomics on the hot S
// array with ~16 contending waves/address can retire in 1000s of cycles,
// stalling all 4 pipes every tile. Change: NO global atomics/stores between
// barriers. Column partials -> cs_all[5][4] registers (tile loop fully
// unrolled+guarded so indexing is static, rule #20); all reduces+atomics
// flushed once after the loop; final tile barrier dropped. Barriers now
// drain only the staging loads issued one full tile earlier.
//
// ws layout: [S: N floats][pos: N floats][zn8: N*D fp8 bytes]

#define N_TOT 8192
#define BATCH 4096
#define DIM   256                    // fp8 bytes per row
#define NT_TILES 64                  // 8192 / 128
#define LOG2E_T 14.4269504089f       // 10 * log2(e)  (temperature folded)

typedef int   v8i32 __attribute__((ext_vector_type(8)));
typedef float f32x4 __attribute__((ext_vector_type(4)));

__device__ __forceinline__ void load_lds16(const void* g, void* l) {
  __builtin_amdgcn_global_load_lds(
      (const __attribute__((address_space(1))) unsigned int*)g,
      (__attribute__((address_space(3))) unsigned int*)l,
      16, 0, 0);
}

// One wave per row: 64 lanes x float4 -> 4 fp8 bytes/lane. Also zeros S
// and the output accumulator.
__global__ __launch_bounds__(256) void normalize_kernel(
    const float* __restrict__ z, unsigned char* __restrict__ zn8,
    float* __restrict__ S, float* __restrict__ out) {
  const int wave = threadIdx.x >> 6;
  const int lane = threadIdx.x & 63;
  const int row  = blockIdx.x * 4 + wave;
  float4 v = ((const float4*)(z + (size_t)row * DIM))[lane];
  float ss = v.x * v.x + v.y * v.y + v.z * v.z + v.w * v.w;
#pragma unroll
  for (int m = 1; m <= 32; m <<= 1) ss += __shfl_xor(ss, m);
  float inv = 1.0f / sqrtf(ss);
  int p01 = __builtin_amdgcn_cvt_pk_fp8_f32(v.x * inv, v.y * inv, 0, false);
  int p23 = __builtin_amdgcn_cvt_pk_fp8_f32(v.z * inv, v.w * inv, 0, false);
  unsigned int packed =
      ((unsigned int)p01 & 0xffffu) | ((unsigned int)p23 << 16);
  ((unsigned int*)(zn8 + (size_t)row * DIM))[lane] = packed;
  if (threadIdx.x < 4) S[blockIdx.x * 4 + threadIdx.x] = 0.0f;
  if (blockIdx.x == 0 && threadIdx.x == 0) out[0] = 0.0f;
}

// Stage a 128-row band (full K = 256 B/row = 32 KB) into LDS, 4 waves.
// Per issue a wave writes 4 rows x 256 B = 1 KB; lane l -> row +(l>>4),
// LDS 16B-chunk (l&15); fetches global chunk (l&15)^(row&15) (XOR swizzle
// keeps fragment ds_read_b128 bank-balanced; measured 0 conflicts).
// LDS dest == wave-uniform base + lane*16 (global_load_lds constraint).
__device__ __forceinline__ void stage_band(
    const unsigned char* __restrict__ zn8, unsigned char* lds, int band,
    int wave, int lane) {
  const int srow = lane >> 4;          // 0..3
  const int slds = lane & 15;          // LDS chunk within row
  const size_t r0 = (size_t)band * 128;
#pragma unroll
  for (int t = 0; t < 8; ++t) {
    const int rloc = wave * 32 + t * 4 + srow;          // 0..127
    const int gch  = slds ^ (rloc & 15);                // swizzled source
    load_lds16(zn8 + (r0 + rloc) * DIM + gch * 16,
               lds + rloc * 256 + slds * 16);
  }
}

// Read one (row, k-half) fragment (32 bytes) from a swizzled band.
__device__ __forceinline__ v8i32 read_frag(const unsigned char* lds, int row,
                                           int h, int quad) {
  const int4* R = (const int4*)(lds + (size_t)row * 256);
  const int base = 8 * h + 2 * quad;   // even global chunk of this lane
  const int cc = row & 15;
  int4 lo = R[base ^ cc];
  int4 hi = R[(base + 1) ^ cc];
  return (v8i32){lo.x, lo.y, lo.z, lo.w, hi.x, hi.y, hi.z, hi.w};
}

// Tile epilogue: register-only. MODE 0 = plain, 1 = diagonal tile (mask
// self-sim), 2 = partner tile (jj==32: emit pos logits; only ever the LAST
// tile, so its stores sit after all barriers). Row sums -> rs[16]; column
// partials -> cs[4] (this tile's slot; reduced+flushed post-loop).
template <int MODE>
__device__ __forceinline__ void epilogue_tile(
    const f32x4 (&acc)[4][4], float (&rs)[16], float (&cs)[4],
    float* __restrict__ pos, int rb, int cbt, int wm, int wn, int c,
    int quad) {
#pragma unroll
  for (int fm = 0; fm < 4; ++fm) {
#pragma unroll
    for (int r = 0; r < 4; ++r) {
      const int grow = rb * 128 + wm * 64 + fm * 16 + quad * 4 + r;
#pragma unroll
      for (int fn = 0; fn < 4; ++fn) {
        const int gcol = cbt * 128 + wn * 64 + fn * 16 + c;
        // exp(acc*10) == exp2(acc * 10*log2(e)); raw v_exp_f32, no libcall
        float e = __builtin_amdgcn_exp2f(acc[fm][fn][r] * LOG2E_T);
        if (MODE == 1 && gcol == grow) e = 0.f;   // exclude self-similarity
        if (MODE == 2 && ((gcol ^ grow) == BATCH)) {
          const float logit = acc[fm][fn][r] * 10.0f;
          pos[grow] = logit;                       // unique writer/elem
          pos[gcol] = logit;                       // sim symmetric
        }
        rs[fm * 4 + r] += e;
        cs[fn] += e;
      }
    }
  }
}

__global__ __launch_bounds__(256, 2) void simclr_tile_kernel(
    const unsigned char* __restrict__ zn8, float* __restrict__ S,
    float* __restrict__ pos) {
  const int g = blockIdx.x;                    // j-group 0..7
  const int rb = blockIdx.y;                   // row band 0..63 (A, fixed)
  const int tid = threadIdx.x;
  const int wave = tid >> 6, lane = tid & 63;
  const int wm = wave >> 1, wn = wave & 1;     // wave quadrant (2x2)
  const int c = lane & 15, quad = lane >> 4;   // MFMA lane coords

  // Two 32KB band buffers. L[1] holds A only until its fragments are in
  // registers, then becomes B's second buffer (double-buffer, no extra LDS).
  __shared__ alignas(16) unsigned char L[2][128 * 256];   // 64 KB

  const int ntile = (g == 0 && rb < 32) ? 5 : 4;  // g0 also does j=32

  stage_band(zn8, L[0], (rb + g * 4) & 63, wave, lane);   // B for tile 0
  stage_band(zn8, L[1], rb, wave, lane);                  // A (transient)
  __syncthreads();

  // A-fragments -> registers, reused across all tiles of this block.
  v8i32 af[4][2];
#pragma unroll
  for (int f = 0; f < 4; ++f)
#pragma unroll
    for (int h = 0; h < 2; ++h)
      af[f][h] = read_frag(L[1], wm * 64 + f * 16 + c, h, quad);
  __syncthreads();   // all waves done with A; L[1] is now B buf[1]

  // Per-row exp-sums (whole block) and per-tile column partials. The tile
  // loop is fully unrolled with a uniform guard so cs_all indexing is
  // compile-time (runtime-indexed arrays would spill to scratch).
  float rs[16];
#pragma unroll
  for (int i = 0; i < 16; ++i) rs[i] = 0.f;
  float cs_all[5][4];
#pragma unroll
  for (int t = 0; t < 5; ++t)
#pragma unroll
    for (int k = 0; k < 4; ++k) cs_all[t][k] = 0.f;

#pragma unroll
  for (int t = 0; t < 5; ++t) {
    if (t < ntile) {                           // block-uniform guard
      const int jj = (t == 4) ? 32 : (g * 4 + t);
      const int cbt = (rb + jj) & 63;

      // Issue next-tile staging FIRST into the other buffer (last read at
      // tile t-1, safe since the barrier ending t-1); drains at this
      // tile's end barrier -> full-tile latency window.
      if (t + 1 < ntile) {
        const int jn = (t + 1 == 4) ? 32 : (g * 4 + t + 1);
        stage_band(zn8, L[(t + 1) & 1], (rb + jn) & 63, wave, lane);
      }

      const unsigned char* Bcur = L[t & 1];
      f32x4 acc[4][4];
#pragma unroll
      for (int i = 0; i < 4; ++i)
#pragma unroll
        for (int k = 0; k < 4; ++k) acc[i][k] = (f32x4){0.f, 0.f, 0.f, 0.f};

#pragma unroll
      for (int h = 0; h < 2; ++h) {
        v8i32 bfr[4];
#pragma unroll
        for (int f = 0; f < 4; ++f)
          bfr[f] = read_frag(Bcur, wn * 64 + f * 16 + c, h, quad);
#pragma unroll
        for (int fm = 0; fm < 4; ++fm)
#pragma unroll
          for (int fn = 0; fn < 4; ++fn)
            acc[fm][fn] = __builtin_amdgcn_mfma_scale_f32_16x16x128_f8f6f4(
                af[fm][h], bfr[fn], acc[fm][fn],
                0, 0,                 // cbsz = fp8(A), blgp = fp8(B)
                0, 0x7f,              // opsel_a, scale_a = E8M0 1.0
                0, 0x7f);             // opsel_b, scale_b = E8M0 1.0
      }

      // Register-only epilogue (t is compile-time here).
      if (t == 0) {
        if (g == 0)
          epilogue_tile<1>(acc, rs, cs_all[0], pos, rb, cbt, wm, wn, c, quad);
        else
          epilogue_tile<0>(acc, rs, cs_all[0], pos, rb, cbt, wm, wn, c, quad);
      } else if (t == 4) {
        epilogue_tile<2>(acc, rs, cs_all[4], pos, rb, cbt, wm, wn, c, quad);
      } else {
        epilogue_tile<0>(acc, rs, cs_all[t], pos, rb, cbt, wm, wn, c, quad);
      }

      // Barrier only between tiles; drains staging loads (issued one full
      // tile ago) and protects Bcur from restage. No atomics outstanding.
      if (t + 1 < ntile) __syncthreads();
    }
  }

  // ---- Post-loop flush: all shuffles + atomics live here, after the last
  // barrier, so they never serialize the pipeline. ----

  // Row sums: one shuffle-reduce + atomic per row.
#pragma unroll
  for (int fm = 0; fm < 4; ++fm) {
#pragma unroll
    for (int r = 0; r < 4; ++r) {
      float s = rs[fm * 4 + r];
      s += __shfl_xor(s, 1);
      s += __shfl_xor(s, 2);
      s += __shfl_xor(s, 4);
      s += __shfl_xor(s, 8);
      if (c == 0) {
        const int grow = rb * 128 + wm * 64 + fm * 16 + quad * 4 + r;
        atomicAdd(&S[grow], s);
      }
    }
  }

  // Column sums per tile (skip diag tile: symmetric, row sums cover it).
#pragma unroll
  for (int t = 0; t < 5; ++t) {
    if (t < ntile && !(g == 0 && t == 0)) {
      const int jj = (t == 4) ? 32 : (g * 4 + t);
      const int cbt = (rb + jj) & 63;
#pragma unroll
      for (int fn = 0; fn < 4; ++fn) {
        float v = cs_all[t][fn];
        v += __shfl_xor(v, 16);
        v += __shfl_xor(v, 32);
        if (quad == 0)
          atomicAdd(&S[cbt * 128 + wn * 64 + fn * 16 + c], v);
      }
    }
  }
}

// loss = mean(log(S_i) - pos_i); 16 blocks, atomic accumulate into out.
__global__ __launch_bounds__(512) void finalize_kernel(
    const float* __restrict__ S, const float* __restrict__ pos,
    float* __restrict__ out) {
  const int i = blockIdx.x * 512 + threadIdx.x;
  float a = __logf(S[i]) - pos[i];
#pragma unroll
  for (int m = 1; m <= 32; m <<= 1) a += __shfl_xor(a, m);
  __shared__ float red[8];
  if ((threadIdx.x & 63) == 0) red[threadIdx.x >> 6] = a;
  __syncthreads();
  if (threadIdx.x < 8) {
    float v = red[threadIdx.x];
    v += __shfl_xor(v, 1);
    v += __shfl_xor(v, 2);
    v += __shfl_xor(v, 4);
    if (threadIdx.x == 0) atomicAdd(out, v * (1.0f / (float)N_TOT));
  }
}

extern "C" void kernel_launch(void* const* d_in, const int* in_sizes, int n_in,
                              void* d_out, int out_size, void* d_ws,
                              size_t ws_size, hipStream_t stream) {
  const float* z = (const float*)d_in[0];
  float* out = (float*)d_out;
  char* ws = (char*)d_ws;
  float* S = (float*)ws;                                   // N floats
  float* pos = (float*)(ws + N_TOT * sizeof(float));       // N floats
  unsigned char* zn8 =
      (unsigned char*)(ws + 2 * N_TOT * sizeof(float));    // N*D fp8

  normalize_kernel<<<N_TOT / 4, 256, 0, stream>>>(z, zn8, S, out);
  dim3 grid(8, NT_TILES);
  simclr_tile_kernel<<<grid, 256, 0, stream>>>(zn8, S, pos);
  finalize_kernel<<<N_TOT / 512, 512, 0, stream>>>(S, pos, out);
}

// Round 5
// 85.344 us; speedup vs baseline: 1.4336x; 1.4336x over previous
//
#include <hip/hip_runtime.h>
#include <hip/hip_bf16.h>

// NT-Xent (SimCLR) fused loss, MI355X gfx950. Round 13: no vmem between
// barriers, spill-free. r12 post-mortem: the register version of this idea
// spilled (FETCH/WRITE ~80MB symmetric scratch traffic) -- invalid test.
// This round keeps r11's runtime tile loop (measured best, VGPR=128, no
// spill) and parks per-tile column partials in a 5KB LDS scratch
// (colpart[5][2][128], unique writer/slot, plain ds_write) instead of
// registers. All global atomics move past the final barrier; per-tile
// __syncthreads drains only staging loads issued one full tile earlier.
//
// ws layout: [S: N floats][pos: N floats][zn8: N*D fp8 bytes]

#define N_TOT 8192
#define BATCH 4096
#define DIM   256                    // fp8 bytes per row
#define NT_TILES 64                  // 8192 / 128
#define LOG2E_T 14.4269504089f       // 10 * log2(e)  (temperature folded)

typedef int   v8i32 __attribute__((ext_vector_type(8)));
typedef float f32x4 __attribute__((ext_vector_type(4)));

__device__ __forceinline__ void load_lds16(const void* g, void* l) {
  __builtin_amdgcn_global_load_lds(
      (const __attribute__((address_space(1))) unsigned int*)g,
      (__attribute__((address_space(3))) unsigned int*)l,
      16, 0, 0);
}

// One wave per row: 64 lanes x float4 -> 4 fp8 bytes/lane. Also zeros S
// and the output accumulator.
__global__ __launch_bounds__(256) void normalize_kernel(
    const float* __restrict__ z, unsigned char* __restrict__ zn8,
    float* __restrict__ S, float* __restrict__ out) {
  const int wave = threadIdx.x >> 6;
  const int lane = threadIdx.x & 63;
  const int row  = blockIdx.x * 4 + wave;
  float4 v = ((const float4*)(z + (size_t)row * DIM))[lane];
  float ss = v.x * v.x + v.y * v.y + v.z * v.z + v.w * v.w;
#pragma unroll
  for (int m = 1; m <= 32; m <<= 1) ss += __shfl_xor(ss, m);
  float inv = 1.0f / sqrtf(ss);
  int p01 = __builtin_amdgcn_cvt_pk_fp8_f32(v.x * inv, v.y * inv, 0, false);
  int p23 = __builtin_amdgcn_cvt_pk_fp8_f32(v.z * inv, v.w * inv, 0, false);
  unsigned int packed =
      ((unsigned int)p01 & 0xffffu) | ((unsigned int)p23 << 16);
  ((unsigned int*)(zn8 + (size_t)row * DIM))[lane] = packed;
  if (threadIdx.x < 4) S[blockIdx.x * 4 + threadIdx.x] = 0.0f;
  if (blockIdx.x == 0 && threadIdx.x == 0) out[0] = 0.0f;
}

// Stage a 128-row band (full K = 256 B/row = 32 KB) into LDS, 4 waves.
// Per issue a wave writes 4 rows x 256 B = 1 KB; lane l -> row +(l>>4),
// LDS 16B-chunk (l&15); fetches global chunk (l&15)^(row&15) (XOR swizzle
// keeps fragment ds_read_b128 bank-balanced; measured 0 conflicts).
// LDS dest == wave-uniform base + lane*16 (global_load_lds constraint).
__device__ __forceinline__ void stage_band(
    const unsigned char* __restrict__ zn8, unsigned char* lds, int band,
    int wave, int lane) {
  const int srow = lane >> 4;          // 0..3
  const int slds = lane & 15;          // LDS chunk within row
  const size_t r0 = (size_t)band * 128;
#pragma unroll
  for (int t = 0; t < 8; ++t) {
    const int rloc = wave * 32 + t * 4 + srow;          // 0..127
    const int gch  = slds ^ (rloc & 15);                // swizzled source
    load_lds16(zn8 + (r0 + rloc) * DIM + gch * 16,
               lds + rloc * 256 + slds * 16);
  }
}

// Read one (row, k-half) fragment (32 bytes) from a swizzled band.
__device__ __forceinline__ v8i32 read_frag(const unsigned char* lds, int row,
                                           int h, int quad) {
  const int4* R = (const int4*)(lds + (size_t)row * 256);
  const int base = 8 * h + 2 * quad;   // even global chunk of this lane
  const int cc = row & 15;
  int4 lo = R[base ^ cc];
  int4 hi = R[(base + 1) ^ cc];
  return (v8i32){lo.x, lo.y, lo.z, lo.w, hi.x, hi.y, hi.z, hi.w};
}

// Tile epilogue: register/LDS only, NO global atomics. MODE 0 = plain,
// 1 = diagonal tile (mask self-sim), 2 = partner tile (jj==32: emit pos
// logits; only ever the LAST tile, after all inter-tile barriers).
// Row sums -> rs[16]; column partials -> cs[4] (caller parks in LDS).
template <int MODE>
__device__ __forceinline__ void epilogue_tile(
    const f32x4 (&acc)[4][4], float (&rs)[16], float (&cs)[4],
    float* __restrict__ pos, int rb, int cbt, int wm, int wn, int c,
    int quad) {
#pragma unroll
  for (int fm = 0; fm < 4; ++fm) {
#pragma unroll
    for (int r = 0; r < 4; ++r) {
      const int grow = rb * 128 + wm * 64 + fm * 16 + quad * 4 + r;
#pragma unroll
      for (int fn = 0; fn < 4; ++fn) {
        const int gcol = cbt * 128 + wn * 64 + fn * 16 + c;
        // exp(acc*10) == exp2(acc * 10*log2(e)); raw v_exp_f32, no libcall
        float e = __builtin_amdgcn_exp2f(acc[fm][fn][r] * LOG2E_T);
        if (MODE == 1 && gcol == grow) e = 0.f;   // exclude self-similarity
        if (MODE == 2 && ((gcol ^ grow) == BATCH)) {
          const float logit = acc[fm][fn][r] * 10.0f;
          pos[grow] = logit;                       // unique writer/elem
          pos[gcol] = logit;                       // sim symmetric
        }
        rs[fm * 4 + r] += e;
        cs[fn] += e;
      }
    }
  }
}

__global__ __launch_bounds__(256, 2) void simclr_tile_kernel(
    const unsigned char* __restrict__ zn8, float* __restrict__ S,
    float* __restrict__ pos) {
  const int g = blockIdx.x;                    // j-group 0..7
  const int rb = blockIdx.y;                   // row band 0..63 (A, fixed)
  const int tid = threadIdx.x;
  const int wave = tid >> 6, lane = tid & 63;
  const int wm = wave >> 1, wn = wave & 1;     // wave quadrant (2x2)
  const int c = lane & 15, quad = lane >> 4;   // MFMA lane coords

  // Two 32KB band buffers. L[1] holds A only until its fragments are in
  // registers, then becomes B's second buffer (double-buffer, no extra LDS).
  __shared__ alignas(16) unsigned char L[2][128 * 256];   // 64 KB
  // Per-tile column partials: slot [t][wm][col], unique writer per slot.
  __shared__ float colpart[5][2][128];                    // 5 KB

  const int ntile = (g == 0 && rb < 32) ? 5 : 4;  // g0 also does j=32

  stage_band(zn8, L[0], (rb + g * 4) & 63, wave, lane);   // B for tile 0
  stage_band(zn8, L[1], rb, wave, lane);                  // A (transient)
  __syncthreads();

  // A-fragments -> registers, reused across all tiles of this block.
  v8i32 af[4][2];
#pragma unroll
  for (int f = 0; f < 4; ++f)
#pragma unroll
    for (int h = 0; h < 2; ++h)
      af[f][h] = read_frag(L[1], wm * 64 + f * 16 + c, h, quad);
  __syncthreads();   // all waves done with A; L[1] is now B buf[1]

  // Per-row exp-sum partials, accumulated across ALL tiles of this block
  // (the wave's 16 output rows are the same for every tile).
  float rs[16];
#pragma unroll
  for (int i = 0; i < 16; ++i) rs[i] = 0.f;

  for (int t = 0; t < ntile; ++t) {
    const int jj = (t == 4) ? 32 : (g * 4 + t);
    const int cbt = (rb + jj) & 63;

    // Issue next-tile staging FIRST into the other buffer (last read at
    // tile t-1, safe since the barrier ending t-1); drains at this tile's
    // end barrier -> full-tile latency window.
    if (t + 1 < ntile) {
      const int jn = (t + 1 == 4) ? 32 : (g * 4 + t + 1);
      stage_band(zn8, L[(t + 1) & 1], (rb + jn) & 63, wave, lane);
    }

    const unsigned char* Bcur = L[t & 1];
    f32x4 acc[4][4];
#pragma unroll
    for (int i = 0; i < 4; ++i)
#pragma unroll
      for (int k = 0; k < 4; ++k) acc[i][k] = (f32x4){0.f, 0.f, 0.f, 0.f};

#pragma unroll
    for (int h = 0; h < 2; ++h) {
      v8i32 bfr[4];
#pragma unroll
      for (int f = 0; f < 4; ++f)
        bfr[f] = read_frag(Bcur, wn * 64 + f * 16 + c, h, quad);
#pragma unroll
      for (int fm = 0; fm < 4; ++fm)
#pragma unroll
        for (int fn = 0; fn < 4; ++fn)
          acc[fm][fn] = __builtin_amdgcn_mfma_scale_f32_16x16x128_f8f6f4(
              af[fm][h], bfr[fn], acc[fm][fn],
              0, 0,                 // cbsz = fp8(A), blgp = fp8(B)
              0, 0x7f,              // opsel_a, scale_a = E8M0 1.0
              0, 0x7f);             // opsel_b, scale_b = E8M0 1.0
    }

    // Register-only epilogue (no global atomics/stores except pos in the
    // final tile, which has no trailing inter-tile barrier).
    float cs[4] = {0.f, 0.f, 0.f, 0.f};
    if (g == 0 && t == 0)
      epilogue_tile<1>(acc, rs, cs, pos, rb, cbt, wm, wn, c, quad);
    else if (t == 4)
      epilogue_tile<2>(acc, rs, cs, pos, rb, cbt, wm, wn, c, quad);
    else
      epilogue_tile<0>(acc, rs, cs, pos, rb, cbt, wm, wn, c, quad);

    // Column partial: 2-shuffle reduce, park in LDS (plain ds_write,
    // unique writer per slot). Diag tile skipped (symmetric; rows cover).
    if (!(g == 0 && t == 0)) {
#pragma unroll
      for (int fn = 0; fn < 4; ++fn) {
        float v = cs[fn];
        v += __shfl_xor(v, 16);
        v += __shfl_xor(v, 32);
        if (quad == 0) colpart[t][wm][wn * 64 + fn * 16 + c] = v;
      }
    }

    // Barrier only between tiles; drains staging loads (issued one full
    // tile ago) and protects Bcur from restage. No atomics outstanding.
    if (t + 1 < ntile) __syncthreads();
  }

  __syncthreads();   // colpart visible to all waves; nothing else pending

  // ---- Post-loop flush: ALL global atomics live here, after the last
  // barrier, so they never serialize the tile pipeline. ----

  // Row sums: one shuffle-reduce + atomic per row.
#pragma unroll
  for (int fm = 0; fm < 4; ++fm) {
#pragma unroll
    for (int r = 0; r < 4; ++r) {
      float s = rs[fm * 4 + r];
      s += __shfl_xor(s, 1);
      s += __shfl_xor(s, 2);
      s += __shfl_xor(s, 4);
      s += __shfl_xor(s, 8);
      if (c == 0) {
        const int grow = rb * 128 + wm * 64 + fm * 16 + quad * 4 + r;
        atomicAdd(&S[grow], s);
      }
    }
  }

  // Column sums: combine wm-halves from LDS, one atomic per (tile, col).
  for (int idx = tid; idx < ntile * 128; idx += 256) {
    const int t = idx >> 7, col = idx & 127;
    if (!(g == 0 && t == 0)) {
      const int jj = (t == 4) ? 32 : (g * 4 + t);
      const int cbt = (rb + jj) & 63;
      atomicAdd(&S[cbt * 128 + col], colpart[t][0][col] + colpart[t][1][col]);
    }
  }
}

// loss = mean(log(S_i) - pos_i); 16 blocks, atomic accumulate into out.
__global__ __launch_bounds__(512) void finalize_kernel(
    const float* __restrict__ S, const float* __restrict__ pos,
    float* __restrict__ out) {
  const int i = blockIdx.x * 512 + threadIdx.x;
  float a = __logf(S[i]) - pos[i];
#pragma unroll
  for (int m = 1; m <= 32; m <<= 1) a += __shfl_xor(a, m);
  __shared__ float red[8];
  if ((threadIdx.x & 63) == 0) red[threadIdx.x >> 6] = a;
  __syncthreads();
  if (threadIdx.x < 8) {
    float v = red[threadIdx.x];
    v += __shfl_xor(v, 1);
    v += __shfl_xor(v, 2);
    v += __shfl_xor(v, 4);
    if (threadIdx.x == 0) atomicAdd(out, v * (1.0f / (float)N_TOT));
  }
}

extern "C" void kernel_launch(void* const* d_in, const int* in_sizes, int n_in,
                              void* d_out, int out_size, void* d_ws,
                              size_t ws_size, hipStream_t stream) {
  const float* z = (const float*)d_in[0];
  float* out = (float*)d_out;
  char* ws = (char*)d_ws;
  float* S = (float*)ws;                                   // N floats
  float* pos = (float*)(ws + N_TOT * sizeof(float));       // N floats
  unsigned char* zn8 =
      (unsigned char*)(ws + 2 * N_TOT * sizeof(float));    // N*D fp8

  normalize_kernel<<<N_TOT / 4, 256, 0, stream>>>(z, zn8, S, out);
  dim3 grid(8, NT_TILES);
  simclr_tile_kernel<<<grid, 256, 0, stream>>>(zn8, S, pos);
  finalize_kernel<<<N_TOT / 512, 512, 0, stream>>>(S, pos, out);
}

// Round 6
// 78.707 us; speedup vs baseline: 1.5545x; 1.0843x over previous
//
#include <hip/hip_runtime.h>
#include <hip/hip_bf16.h>

// NT-Xent (SimCLR) fused loss, MI355X gfx950. Round 14: NO LDS, NO BARRIERS.
// r13 falsified the atomic-drain theory (post-loop flush neutral). Static
// accounting: ~7us of real work vs ~36us measured -> the staged-lockstep
// skeleton (global_load_lds bands + per-tile __syncthreads at 2 waves/SIMD)
// is the remaining suspect. zn8 is 2MB = L2-resident; staging L2-fit data
// is pure overhead (guide common-mistake #7). This round: normalize emits
// fp8 in FRAGMENT-MAJOR layout znf[G][h][q] (512B blocks, lane c's 32B at
// c*32), so MFMA fragments load directly from L2 with 2x dwordx4 per frag,
// perfectly coalesced. simclr has zero LDS, zero syncthreads: A-frags once,
// per tile 16 B-frag loads -> MFMA -> register epilogue -> per-tile column
// atomics (r11-measured equal to deferred). Waves free-run; wave skew hides
// L2 latency. Same tile enumeration/numerics -> absmax 0.
//
// ws layout: [S: N floats][pos: N floats][znf: N*D fp8 bytes, frag-major]

#define N_TOT 8192
#define BATCH 4096
#define DIM   256                    // fp8 bytes per row
#define NT_TILES 64                  // 8192 / 128
#define LOG2E_T 14.4269504089f       // 10 * log2(e)  (temperature folded)

typedef int   v8i32 __attribute__((ext_vector_type(8)));
typedef float f32x4 __attribute__((ext_vector_type(4)));

// znf layout: for 16-row group G (rows G*16+c, c=0..15), k-half h (0/1),
// quad q (0..3): 512-byte block at ((G*2+h)*4+q)*512. Lane c's 32 bytes
// (row G*16+c, row-bytes [16*(8h+2q), +32)) live contiguously at c*32.

// One wave per row: 64 lanes x float4 -> 4 fp8 bytes/lane, scattered into
// fragment-major znf. Also zeros S and the output accumulator.
__global__ __launch_bounds__(256) void normalize_kernel(
    const float* __restrict__ z, unsigned char* __restrict__ znf,
    float* __restrict__ S, float* __restrict__ out) {
  const int wave = threadIdx.x >> 6;
  const int lane = threadIdx.x & 63;
  const int row  = blockIdx.x * 4 + wave;
  float4 v = ((const float4*)(z + (size_t)row * DIM))[lane];
  float ss = v.x * v.x + v.y * v.y + v.z * v.z + v.w * v.w;
#pragma unroll
  for (int m = 1; m <= 32; m <<= 1) ss += __shfl_xor(ss, m);
  float inv = 1.0f / sqrtf(ss);
  int p01 = __builtin_amdgcn_cvt_pk_fp8_f32(v.x * inv, v.y * inv, 0, false);
  int p23 = __builtin_amdgcn_cvt_pk_fp8_f32(v.z * inv, v.w * inv, 0, false);
  unsigned int packed =
      ((unsigned int)p01 & 0xffffu) | ((unsigned int)p23 << 16);
  // This thread holds row-bytes [4*lane, 4*lane+4) == word w = lane.
  // chunk16 = w>>2; h = w>>5; q = (w>>3)&3; lowhalf = (w>>2)&1.
  const int G = row >> 4, c = row & 15;
  const int h = lane >> 5, q = (lane >> 3) & 3, lb = (lane >> 2) & 1;
  *(unsigned int*)(znf + (((size_t)(G * 2 + h) * 4 + q) << 9) + c * 32 +
                   lb * 16 + (lane & 3) * 4) = packed;
  if (threadIdx.x < 4) S[blockIdx.x * 4 + threadIdx.x] = 0.0f;
  if (blockIdx.x == 0 && threadIdx.x == 0) out[0] = 0.0f;
}

// Load one (row-group, k-half) fragment (32 B/lane) straight from L2.
// Lanes (c, quad) read ((G*2+h)*4+quad)*512 + c*32 -- two dwordx4,
// 2 KB contiguous per wave per instruction pair.
__device__ __forceinline__ v8i32 load_frag_g(
    const unsigned char* __restrict__ znf, int G, int h, int quad, int c) {
  const int4* p =
      (const int4*)(znf + (((size_t)(G * 2 + h) * 4 + quad) << 9) + c * 32);
  int4 lo = p[0];
  int4 hi = p[1];
  return (v8i32){lo.x, lo.y, lo.z, lo.w, hi.x, hi.y, hi.z, hi.w};
}

// Tile epilogue: register-only. MODE 0 = plain, 1 = diagonal tile (mask
// self-sim; col sums skipped by caller -- symmetric, rows cover), 2 =
// partner tile (jj==32: emit pos logits). Row sums -> rs[16] (flushed once
// per block); column partials -> cs[4] (caller reduces + atomics).
template <int MODE>
__device__ __forceinline__ void epilogue_tile(
    const f32x4 (&acc)[4][4], float (&rs)[16], float (&cs)[4],
    float* __restrict__ pos, int rb, int cbt, int wm, int wn, int c,
    int quad) {
#pragma unroll
  for (int fm = 0; fm < 4; ++fm) {
#pragma unroll
    for (int r = 0; r < 4; ++r) {
      const int grow = rb * 128 + wm * 64 + fm * 16 + quad * 4 + r;
#pragma unroll
      for (int fn = 0; fn < 4; ++fn) {
        const int gcol = cbt * 128 + wn * 64 + fn * 16 + c;
        // exp(acc*10) == exp2(acc * 10*log2(e)); raw v_exp_f32, no libcall
        float e = __builtin_amdgcn_exp2f(acc[fm][fn][r] * LOG2E_T);
        if (MODE == 1 && gcol == grow) e = 0.f;   // exclude self-similarity
        if (MODE == 2 && ((gcol ^ grow) == BATCH)) {
          const float logit = acc[fm][fn][r] * 10.0f;
          pos[grow] = logit;                       // unique writer/elem
          pos[gcol] = logit;                       // sim symmetric
        }
        rs[fm * 4 + r] += e;
        cs[fn] += e;
      }
    }
  }
}

__global__ __launch_bounds__(256, 2) void simclr_tile_kernel(
    const unsigned char* __restrict__ znf, float* __restrict__ S,
    float* __restrict__ pos) {
  const int g = blockIdx.x;                    // j-group 0..7
  const int rb = blockIdx.y;                   // row band 0..63 (A, fixed)
  const int tid = threadIdx.x;
  const int wave = tid >> 6, lane = tid & 63;
  const int wm = wave >> 1, wn = wave & 1;     // wave quadrant (2x2)
  const int c = lane & 15, quad = lane >> 4;   // MFMA lane coords

  const int ntile = (g == 0 && rb < 32) ? 5 : 4;  // g0 also does j=32

  // A-fragments -> registers once per block, straight from L2.
  v8i32 af[4][2];
#pragma unroll
  for (int f = 0; f < 4; ++f)
#pragma unroll
    for (int h = 0; h < 2; ++h)
      af[f][h] = load_frag_g(znf, rb * 8 + wm * 4 + f, h, quad, c);

  // Per-row exp-sum partials, accumulated across ALL tiles of this block.
  float rs[16];
#pragma unroll
  for (int i = 0; i < 16; ++i) rs[i] = 0.f;

  for (int t = 0; t < ntile; ++t) {
    const int jj = (t == 4) ? 32 : (g * 4 + t);
    const int cbt = (rb + jj) & 63;

    // All 16 B-fragment loads issued up front (independent, L2-resident);
    // compiler overlaps them with the MFMA chain. No LDS, no barriers.
    v8i32 bf[4][2];
#pragma unroll
    for (int f = 0; f < 4; ++f)
#pragma unroll
      for (int h = 0; h < 2; ++h)
        bf[f][h] = load_frag_g(znf, cbt * 8 + wn * 4 + f, h, quad, c);

    f32x4 acc[4][4];
#pragma unroll
    for (int i = 0; i < 4; ++i)
#pragma unroll
      for (int k = 0; k < 4; ++k) acc[i][k] = (f32x4){0.f, 0.f, 0.f, 0.f};

#pragma unroll
    for (int h = 0; h < 2; ++h)
#pragma unroll
      for (int fm = 0; fm < 4; ++fm)
#pragma unroll
        for (int fn = 0; fn < 4; ++fn)
          acc[fm][fn] = __builtin_amdgcn_mfma_scale_f32_16x16x128_f8f6f4(
              af[fm][h], bf[fn][h], acc[fm][fn],
              0, 0,                 // cbsz = fp8(A), blgp = fp8(B)
              0, 0x7f,              // opsel_a, scale_a = E8M0 1.0
              0, 0x7f);             // opsel_b, scale_b = E8M0 1.0

    // Register epilogue, specialized per tile kind (uniform branch).
    float cs[4] = {0.f, 0.f, 0.f, 0.f};
    if (g == 0 && t == 0)
      epilogue_tile<1>(acc, rs, cs, pos, rb, cbt, wm, wn, c, quad);
    else if (t == 4)
      epilogue_tile<2>(acc, rs, cs, pos, rb, cbt, wm, wn, c, quad);
    else
      epilogue_tile<0>(acc, rs, cs, pos, rb, cbt, wm, wn, c, quad);

    // Column sums -> S[col] (transpose contribution); diag tile skipped
    // (symmetric; row sums cover it). Nothing ever waits on these atomics.
    if (!(g == 0 && t == 0)) {
#pragma unroll
      for (int fn = 0; fn < 4; ++fn) {
        float v = cs[fn];
        v += __shfl_xor(v, 16);
        v += __shfl_xor(v, 32);
        if (quad == 0)
          atomicAdd(&S[cbt * 128 + wn * 64 + fn * 16 + c], v);
      }
    }
  }

  // Flush per-row sums: one shuffle-reduce + atomic per row.
#pragma unroll
  for (int fm = 0; fm < 4; ++fm) {
#pragma unroll
    for (int r = 0; r < 4; ++r) {
      float s = rs[fm * 4 + r];
      s += __shfl_xor(s, 1);
      s += __shfl_xor(s, 2);
      s += __shfl_xor(s, 4);
      s += __shfl_xor(s, 8);
      if (c == 0) {
        const int grow = rb * 128 + wm * 64 + fm * 16 + quad * 4 + r;
        atomicAdd(&S[grow], s);
      }
    }
  }
}

// loss = mean(log(S_i) - pos_i); 16 blocks, atomic accumulate into out.
__global__ __launch_bounds__(512) void finalize_kernel(
    const float* __restrict__ S, const float* __restrict__ pos,
    float* __restrict__ out) {
  const int i = blockIdx.x * 512 + threadIdx.x;
  float a = __logf(S[i]) - pos[i];
#pragma unroll
  for (int m = 1; m <= 32; m <<= 1) a += __shfl_xor(a, m);
  __shared__ float red[8];
  if ((threadIdx.x & 63) == 0) red[threadIdx.x >> 6] = a;
  __syncthreads();
  if (threadIdx.x < 8) {
    float v = red[threadIdx.x];
    v += __shfl_xor(v, 1);
    v += __shfl_xor(v, 2);
    v += __shfl_xor(v, 4);
    if (threadIdx.x == 0) atomicAdd(out, v * (1.0f / (float)N_TOT));
  }
}

extern "C" void kernel_launch(void* const* d_in, const int* in_sizes, int n_in,
                              void* d_out, int out_size, void* d_ws,
                              size_t ws_size, hipStream_t stream) {
  const float* z = (const float*)d_in[0];
  float* out = (float*)d_out;
  char* ws = (char*)d_ws;
  float* S = (float*)ws;                                   // N floats
  float* pos = (float*)(ws + N_TOT * sizeof(float));       // N floats
  unsigned char* znf =
      (unsigned char*)(ws + 2 * N_TOT * sizeof(float));    // N*D fp8

  normalize_kernel<<<N_TOT / 4, 256, 0, stream>>>(z, znf, S, out);
  dim3 grid(8, NT_TILES);
  simclr_tile_kernel<<<grid, 256, 0, stream>>>(znf, S, pos);
  finalize_kernel<<<N_TOT / 512, 512, 0, stream>>>(S, pos, out);
}